// Round 3
// baseline (422.731 us; speedup 1.0000x reference)
//
#include <hip/hip_runtime.h>

#define D 384
#define D4 96       // D / 4
#define NPH 4       // source-range phases; slice = N/4 * 1536B = 3.84 MB <= 4 MB per-XCD L2
#define SLOTS_P 32  // per (node, range) bucket; deg per range ~ Poisson(4), P(>32) ~ 0

typedef float vfloat4 __attribute__((ext_vector_type(4)));

// ---------------------------------------------------------------------------
// Kernel 1 (fused): block-level q-norm + per-edge cosine sim + scatter into
// source-range-partitioned buckets. 4 edges per WAVE (16 per 256-thread
// block); two consecutive ea rows = 192 float4 = exactly 3 float4/lane, so
// all 64 lanes load 6 x 16B up front (latency hidden), then 8 interleaved
// butterfly reductions. sim = (v.q_raw) / (|v||q|).
// ---------------------------------------------------------------------------
__global__ __launch_bounds__(256) void edge_kernel(
        const float* __restrict__ ea, const float* __restrict__ q,
        const int* __restrict__ src, const int* __restrict__ dst,
        int* __restrict__ cnt4, int2* __restrict__ bucket4, int E, int range) {
    __shared__ float s_q[D];
    __shared__ float s_red[4];
    __shared__ float s_invq;
    int t = threadIdx.x;

    // stage q raw + block-reduce sum of squares (redundant per block; ~free)
    float ssq = 0.f;
    for (int i = t; i < D; i += 256) { float v = q[i]; s_q[i] = v; ssq += v * v; }
    for (int s = 32; s > 0; s >>= 1) ssq += __shfl_down(ssq, s);
    if ((t & 63) == 0) s_red[t >> 6] = ssq;
    __syncthreads();
    if (t == 0)
        s_invq = 1.0f / fmaxf(sqrtf(s_red[0] + s_red[1] + s_red[2] + s_red[3]), 1e-12f);
    __syncthreads();

    int wave = t >> 6, lane = t & 63;
    int e0 = (blockIdx.x * 4 + wave) * 4;   // 4 edges per wave (2 pairs)
    if (e0 >= E) return;

    const vfloat4* q4 = (const vfloat4*)s_q;
    bool lo = lane < 32;

    if (e0 + 4 <= E) {
        // ---- fast path: 2 full pairs ----
        vfloat4 qc0 = q4[lane];
        vfloat4 qc1 = lo ? q4[lane + 64] : q4[lane - 32];
        vfloat4 qc2 = q4[lane + 32];

        const vfloat4* sp0 = (const vfloat4*)(ea + (size_t)e0 * D);        // rows e0, e0+1
        const vfloat4* sp1 = (const vfloat4*)(ea + (size_t)(e0 + 2) * D);  // rows e0+2, e0+3

        vfloat4 a0 = __builtin_nontemporal_load(&sp0[lane]);
        vfloat4 b0 = __builtin_nontemporal_load(&sp0[lane + 64]);
        vfloat4 c0 = __builtin_nontemporal_load(&sp0[lane + 128]);
        vfloat4 a1 = __builtin_nontemporal_load(&sp1[lane]);
        vfloat4 b1 = __builtin_nontemporal_load(&sp1[lane + 64]);
        vfloat4 c1 = __builtin_nontemporal_load(&sp1[lane + 128]);

        float dA0 = a0.x*qc0.x + a0.y*qc0.y + a0.z*qc0.z + a0.w*qc0.w;
        float sA0 = a0.x*a0.x + a0.y*a0.y + a0.z*a0.z + a0.w*a0.w;
        float db0 = b0.x*qc1.x + b0.y*qc1.y + b0.z*qc1.z + b0.w*qc1.w;
        float sb0 = b0.x*b0.x + b0.y*b0.y + b0.z*b0.z + b0.w*b0.w;
        float dB0 = c0.x*qc2.x + c0.y*qc2.y + c0.z*qc2.z + c0.w*qc2.w;
        float sB0 = c0.x*c0.x + c0.y*c0.y + c0.z*c0.z + c0.w*c0.w;
        if (lo) { dA0 += db0; sA0 += sb0; }
        else    { dB0 += db0; sB0 += sb0; }

        float dA1 = a1.x*qc0.x + a1.y*qc0.y + a1.z*qc0.z + a1.w*qc0.w;
        float sA1 = a1.x*a1.x + a1.y*a1.y + a1.z*a1.z + a1.w*a1.w;
        float db1 = b1.x*qc1.x + b1.y*qc1.y + b1.z*qc1.z + b1.w*qc1.w;
        float sb1 = b1.x*b1.x + b1.y*b1.y + b1.z*b1.z + b1.w*b1.w;
        float dB1 = c1.x*qc2.x + c1.y*qc2.y + c1.z*qc2.z + c1.w*qc2.w;
        float sB1 = c1.x*c1.x + c1.y*c1.y + c1.z*c1.z + c1.w*c1.w;
        if (lo) { dA1 += db1; sA1 += sb1; }
        else    { dB1 += db1; sB1 += sb1; }

        for (int s = 1; s < 64; s <<= 1) {
            dA0 += __shfl_xor(dA0, s); sA0 += __shfl_xor(sA0, s);
            dB0 += __shfl_xor(dB0, s); sB0 += __shfl_xor(sB0, s);
            dA1 += __shfl_xor(dA1, s); sA1 += __shfl_xor(sA1, s);
            dB1 += __shfl_xor(dB1, s); sB1 += __shfl_xor(sB1, s);
        }

        if (lane < 4) {
            int e = e0 + lane;
            float dt = (lane == 0) ? dA0 : (lane == 1) ? dB0 : (lane == 2) ? dA1 : dB1;
            float s2 = (lane == 0) ? sA0 : (lane == 1) ? sB0 : (lane == 2) ? sA1 : sB1;
            float sim = dt * s_invq / fmaxf(sqrtf(s2), 1e-12f);
            int n = dst[e];
            int sv = src[e];
            int idx = n * NPH + sv / range;          // range-partitioned sub-bucket
            int p = atomicAdd(&cnt4[idx], 1);
            if (p < SLOTS_P)  // never taken for this input; safety only
                bucket4[(size_t)idx * SLOTS_P + p] = make_int2(sv, __float_as_int(sim));
        }
    } else {
        // ---- tail path (<4 edges left): one-edge-per-wave scheme ----
        int ne = E - e0;
        for (int j = 0; j < ne; ++j) {
            const vfloat4* row = (const vfloat4*)(ea + (size_t)(e0 + j) * D);
            vfloat4 v = __builtin_nontemporal_load(&row[lane]);
            vfloat4 qq = q4[lane];
            float dot = v.x*qq.x + v.y*qq.y + v.z*qq.z + v.w*qq.w;
            float ss  = v.x*v.x + v.y*v.y + v.z*v.z + v.w*v.w;
            if (lo) {
                vfloat4 v2 = __builtin_nontemporal_load(&row[lane + 64]);
                vfloat4 q2 = q4[lane + 64];
                dot += v2.x*q2.x + v2.y*q2.y + v2.z*q2.z + v2.w*q2.w;
                ss  += v2.x*v2.x + v2.y*v2.y + v2.z*v2.z + v2.w*v2.w;
            }
            for (int s = 32; s > 0; s >>= 1) {
                dot += __shfl_down(dot, s);
                ss  += __shfl_down(ss, s);
            }
            if (lane == 0) {
                float sim = dot * s_invq / fmaxf(sqrtf(ss), 1e-12f);
                int n = dst[e0 + j];
                int sv = src[e0 + j];
                int idx = n * NPH + sv / range;
                int p = atomicAdd(&cnt4[idx], 1);
                if (p < SLOTS_P)
                    bucket4[(size_t)idx * SLOTS_P + p] = make_int2(sv, __float_as_int(sim));
            }
        }
    }
}

// ---------------------------------------------------------------------------
// Kernel 2: ONE PHASE of one layer (source-blocked SpMM). Block (128 thr,
// 96 active) per node; phase PH gathers only sources in [PH*range,(PH+1)*range)
// so the per-XCD working set is ~3.84 MB -> L2-resident. Stream-ordered
// launches align all blocks to the same phase. Partial sums carried in a
// global buffer; PH==3 fuses the finalize:
//   x_out[n] = 0.5*x_in[n] + 0.5 * partial_total / max(deg,1)
// No LDS, no barriers.
// ---------------------------------------------------------------------------
template<int PH>
__global__ __launch_bounds__(128) void agg_phase_kernel(
        const float* __restrict__ xin, const int* __restrict__ cnt4,
        const int2* __restrict__ bucket4, float* __restrict__ partial,
        float* __restrict__ xout, int N) {
    int n = blockIdx.x;
    int t = threadIdx.x;
    if (t >= D4) return;

    int4 c4 = ((const int4*)cnt4)[n];                 // 16B-aligned counts
    int cp = (PH == 0) ? c4.x : (PH == 1) ? c4.y : (PH == 2) ? c4.z : c4.w;
    int m = min(cp, SLOTS_P);

    const int2* bk = bucket4 + ((size_t)n * NPH + PH) * SLOTS_P;
    const float4* xin4 = (const float4*)xin;
    int r = t;

    float4 acc = make_float4(0.f, 0.f, 0.f, 0.f);
    int k = 0;
    for (; k + 3 < m; k += 4) {                        // 4 independent gathers in flight
        int2 e0 = bk[k], e1 = bk[k + 1], e2 = bk[k + 2], e3 = bk[k + 3];
        float4 v0 = xin4[(size_t)e0.x * D4 + r];
        float4 v1 = xin4[(size_t)e1.x * D4 + r];
        float4 v2 = xin4[(size_t)e2.x * D4 + r];
        float4 v3 = xin4[(size_t)e3.x * D4 + r];
        float w0 = __int_as_float(e0.y), w1 = __int_as_float(e1.y);
        float w2 = __int_as_float(e2.y), w3 = __int_as_float(e3.y);
        acc.x += v0.x*w0 + v1.x*w1 + v2.x*w2 + v3.x*w3;
        acc.y += v0.y*w0 + v1.y*w1 + v2.y*w2 + v3.y*w3;
        acc.z += v0.z*w0 + v1.z*w1 + v2.z*w2 + v3.z*w3;
        acc.w += v0.w*w0 + v1.w*w1 + v2.w*w2 + v3.w*w3;
    }
    for (; k < m; ++k) {
        int2 e0 = bk[k];
        float4 v0 = xin4[(size_t)e0.x * D4 + r];
        float w0 = __int_as_float(e0.y);
        acc.x += v0.x*w0; acc.y += v0.y*w0; acc.z += v0.z*w0; acc.w += v0.w*w0;
    }

    size_t o = (size_t)n * D4 + r;
    if (PH != 0) {
        float4 pp = ((const float4*)partial)[o];
        acc.x += pp.x; acc.y += pp.y; acc.z += pp.z; acc.w += pp.w;
    }
    if (PH != NPH - 1) {
        ((float4*)partial)[o] = acc;
    } else {
        int deg = c4.x + c4.y + c4.z + c4.w;
        float scale = 0.5f / fmaxf((float)deg, 1.0f);
        float4 xi = xin4[o];
        float4 ov;
        ov.x = 0.5f*xi.x + acc.x*scale;
        ov.y = 0.5f*xi.y + acc.y*scale;
        ov.z = 0.5f*xi.z + acc.z*scale;
        ov.w = 0.5f*xi.w + acc.w*scale;
        ((float4*)xout)[o] = ov;
    }
}

// ---------------------------------------------------------------------------
extern "C" void kernel_launch(void* const* d_in, const int* in_sizes, int n_in,
                              void* d_out, int out_size, void* d_ws, size_t ws_size,
                              hipStream_t stream) {
    const float* x   = (const float*)d_in[0];
    const int*   ei  = (const int*)d_in[1];
    const float* ea  = (const float*)d_in[2];
    const float* qe  = (const float*)d_in[3];

    const int N = in_sizes[0] / D;      // 10000
    const int E = in_sizes[1] / 2;      // 160000
    const int* src = ei;
    const int* dst = ei + E;
    const int range = (N + NPH - 1) / NPH;

    char* w = (char*)d_ws;
    size_t off = 0;
    auto alloc = [&](size_t bytes) {
        char* p = w + off;
        off = (off + bytes + 255) & ~(size_t)255;
        return p;
    };
    int*   cnt4    = (int*)  alloc((size_t)N * NPH * 4);              // 160 KB
    int2*  bucket4 = (int2*) alloc((size_t)N * NPH * SLOTS_P * 8);    // 10.24 MB
    float* xbuf    = (float*)alloc((size_t)N * D * 4);                // 15.36 MB
    float* partial;
    if (off + (size_t)N * D * 4 <= ws_size) {
        partial = (float*)alloc((size_t)N * D * 4);                   // 15.36 MB
    } else {
        // workspace-tight fallback: d_out doubles as the partial buffer
        // (safe: each layer fully rewrites it; finalize reads partial[o]
        // before writing the same o)
        partial = (float*)d_out;
    }
    (void)n_in; (void)out_size;

    (void)hipMemsetAsync(cnt4, 0, (size_t)N * NPH * 4, stream);
    edge_kernel<<<(E + 15) / 16, 256, 0, stream>>>(ea, qe, src, dst, cnt4, bucket4, E, range);

    // layer 1: x -> xbuf
    agg_phase_kernel<0><<<N, 128, 0, stream>>>(x, cnt4, bucket4, partial, nullptr, N);
    agg_phase_kernel<1><<<N, 128, 0, stream>>>(x, cnt4, bucket4, partial, nullptr, N);
    agg_phase_kernel<2><<<N, 128, 0, stream>>>(x, cnt4, bucket4, partial, nullptr, N);
    agg_phase_kernel<3><<<N, 128, 0, stream>>>(x, cnt4, bucket4, partial, xbuf, N);

    // layer 2: xbuf -> out
    agg_phase_kernel<0><<<N, 128, 0, stream>>>(xbuf, cnt4, bucket4, partial, nullptr, N);
    agg_phase_kernel<1><<<N, 128, 0, stream>>>(xbuf, cnt4, bucket4, partial, nullptr, N);
    agg_phase_kernel<2><<<N, 128, 0, stream>>>(xbuf, cnt4, bucket4, partial, nullptr, N);
    agg_phase_kernel<3><<<N, 128, 0, stream>>>(xbuf, cnt4, bucket4, partial, (float*)d_out, N);
}

// Round 4
// 389.070 us; speedup vs baseline: 1.0865x; 1.0865x over previous
//
#include <hip/hip_runtime.h>
#include <hip/hip_fp16.h>

#define D 384
#define D4 96      // float4s per fp32 row
#define DH 96      // uint2s (4 halfs) per fp16 row: 384*2B = 768B = 96*8B
#define SLOTS 96   // max degree bucket; dst ~ Poisson(16), P(deg>96) ~ 0

typedef float vfloat4 __attribute__((ext_vector_type(4)));

__device__ __forceinline__ float4 h4_to_f4(uint2 u) {
    __half2 h0 = *(__half2*)&u.x;
    __half2 h1 = *(__half2*)&u.y;
    float2 f0 = __half22float2(h0);
    float2 f1 = __half22float2(h1);
    return make_float4(f0.x, f0.y, f1.x, f1.y);
}

__device__ __forceinline__ uint2 f4_to_h4(float4 v) {
    __half2 h0 = __float22half2_rn(make_float2(v.x, v.y));
    __half2 h1 = __float22half2_rn(make_float2(v.z, v.w));
    uint2 u;
    u.x = *(unsigned int*)&h0;
    u.y = *(unsigned int*)&h1;
    return u;
}

// ---------------------------------------------------------------------------
// Kernel 0: x (fp32) -> x16 (fp16 rows) for the gather path. 23 MB of traffic.
// ---------------------------------------------------------------------------
__global__ __launch_bounds__(256) void tohalf_kernel(
        const float* __restrict__ in, uint2* __restrict__ out16, int total4) {
    for (int i = blockIdx.x * 256 + threadIdx.x; i < total4; i += gridDim.x * 256) {
        float4 v = ((const float4*)in)[i];
        out16[i] = f4_to_h4(v);
    }
}

// ---------------------------------------------------------------------------
// Kernel 1 (fused): block-level q-norm + per-edge cosine sim + bucket scatter.
// 4 edges per WAVE (16 per 256-thread block); two consecutive ea rows =
// 192 float4 = exactly 3 float4/lane, all 64 lanes load 6 x 16B up front,
// then 8 interleaved butterfly reductions. sim = (v.q_raw) / (|v||q|).
// (Unchanged from the 394 us best configuration.)
// ---------------------------------------------------------------------------
__global__ __launch_bounds__(256) void edge_kernel(
        const float* __restrict__ ea, const float* __restrict__ q,
        const int* __restrict__ src, const int* __restrict__ dst,
        int* __restrict__ cnt, int2* __restrict__ bucket, int E) {
    __shared__ float s_q[D];
    __shared__ float s_red[4];
    __shared__ float s_invq;
    int t = threadIdx.x;

    float ssq = 0.f;
    for (int i = t; i < D; i += 256) { float v = q[i]; s_q[i] = v; ssq += v * v; }
    for (int s = 32; s > 0; s >>= 1) ssq += __shfl_down(ssq, s);
    if ((t & 63) == 0) s_red[t >> 6] = ssq;
    __syncthreads();
    if (t == 0)
        s_invq = 1.0f / fmaxf(sqrtf(s_red[0] + s_red[1] + s_red[2] + s_red[3]), 1e-12f);
    __syncthreads();

    int wave = t >> 6, lane = t & 63;
    int e0 = (blockIdx.x * 4 + wave) * 4;
    if (e0 >= E) return;

    const vfloat4* q4 = (const vfloat4*)s_q;
    bool lo = lane < 32;

    if (e0 + 4 <= E) {
        vfloat4 qc0 = q4[lane];
        vfloat4 qc1 = lo ? q4[lane + 64] : q4[lane - 32];
        vfloat4 qc2 = q4[lane + 32];

        const vfloat4* sp0 = (const vfloat4*)(ea + (size_t)e0 * D);
        const vfloat4* sp1 = (const vfloat4*)(ea + (size_t)(e0 + 2) * D);

        vfloat4 a0 = __builtin_nontemporal_load(&sp0[lane]);
        vfloat4 b0 = __builtin_nontemporal_load(&sp0[lane + 64]);
        vfloat4 c0 = __builtin_nontemporal_load(&sp0[lane + 128]);
        vfloat4 a1 = __builtin_nontemporal_load(&sp1[lane]);
        vfloat4 b1 = __builtin_nontemporal_load(&sp1[lane + 64]);
        vfloat4 c1 = __builtin_nontemporal_load(&sp1[lane + 128]);

        float dA0 = a0.x*qc0.x + a0.y*qc0.y + a0.z*qc0.z + a0.w*qc0.w;
        float sA0 = a0.x*a0.x + a0.y*a0.y + a0.z*a0.z + a0.w*a0.w;
        float db0 = b0.x*qc1.x + b0.y*qc1.y + b0.z*qc1.z + b0.w*qc1.w;
        float sb0 = b0.x*b0.x + b0.y*b0.y + b0.z*b0.z + b0.w*b0.w;
        float dB0 = c0.x*qc2.x + c0.y*qc2.y + c0.z*qc2.z + c0.w*qc2.w;
        float sB0 = c0.x*c0.x + c0.y*c0.y + c0.z*c0.z + c0.w*c0.w;
        if (lo) { dA0 += db0; sA0 += sb0; }
        else    { dB0 += db0; sB0 += sb0; }

        float dA1 = a1.x*qc0.x + a1.y*qc0.y + a1.z*qc0.z + a1.w*qc0.w;
        float sA1 = a1.x*a1.x + a1.y*a1.y + a1.z*a1.z + a1.w*a1.w;
        float db1 = b1.x*qc1.x + b1.y*qc1.y + b1.z*qc1.z + b1.w*qc1.w;
        float sb1 = b1.x*b1.x + b1.y*b1.y + b1.z*b1.z + b1.w*b1.w;
        float dB1 = c1.x*qc2.x + c1.y*qc2.y + c1.z*qc2.z + c1.w*qc2.w;
        float sB1 = c1.x*c1.x + c1.y*c1.y + c1.z*c1.z + c1.w*c1.w;
        if (lo) { dA1 += db1; sA1 += sb1; }
        else    { dB1 += db1; sB1 += sb1; }

        for (int s = 1; s < 64; s <<= 1) {
            dA0 += __shfl_xor(dA0, s); sA0 += __shfl_xor(sA0, s);
            dB0 += __shfl_xor(dB0, s); sB0 += __shfl_xor(sB0, s);
            dA1 += __shfl_xor(dA1, s); sA1 += __shfl_xor(sA1, s);
            dB1 += __shfl_xor(dB1, s); sB1 += __shfl_xor(sB1, s);
        }

        if (lane < 4) {
            int e = e0 + lane;
            float dt = (lane == 0) ? dA0 : (lane == 1) ? dB0 : (lane == 2) ? dA1 : dB1;
            float s2 = (lane == 0) ? sA0 : (lane == 1) ? sB0 : (lane == 2) ? sA1 : sB1;
            float sim = dt * s_invq / fmaxf(sqrtf(s2), 1e-12f);
            int n = dst[e];
            int p = atomicAdd(&cnt[n], 1);
            if (p < SLOTS)  // never taken for this input; safety only
                bucket[(size_t)n * SLOTS + p] = make_int2(src[e], __float_as_int(sim));
        }
    } else {
        int ne = E - e0;
        for (int j = 0; j < ne; ++j) {
            const vfloat4* row = (const vfloat4*)(ea + (size_t)(e0 + j) * D);
            vfloat4 v = __builtin_nontemporal_load(&row[lane]);
            vfloat4 qq = q4[lane];
            float dot = v.x*qq.x + v.y*qq.y + v.z*qq.z + v.w*qq.w;
            float ss  = v.x*v.x + v.y*v.y + v.z*v.z + v.w*v.w;
            if (lo) {
                vfloat4 v2 = __builtin_nontemporal_load(&row[lane + 64]);
                vfloat4 q2 = q4[lane + 64];
                dot += v2.x*q2.x + v2.y*q2.y + v2.z*q2.z + v2.w*q2.w;
                ss  += v2.x*v2.x + v2.y*v2.y + v2.z*v2.z + v2.w*v2.w;
            }
            for (int s = 32; s > 0; s >>= 1) {
                dot += __shfl_down(dot, s);
                ss  += __shfl_down(ss, s);
            }
            if (lane == 0) {
                float sim = dot * s_invq / fmaxf(sqrtf(ss), 1e-12f);
                int n = dst[e0 + j];
                int p = atomicAdd(&cnt[n], 1);
                if (p < SLOTS)
                    bucket[(size_t)n * SLOTS + p] = make_int2(src[e0 + j], __float_as_int(sim));
            }
        }
    }
}

// ---------------------------------------------------------------------------
// Kernel 2: one layer. Block (384 thr) per node; 4 groups of 96; group g
// handles edges k+g, thread r owns 4-half chunk r of the row. Gathers read
// the fp16 copy (8B/thread, HALF the traffic of fp32); accumulation and the
// self term stay fp32. 4-deep unroll. If WRITE16, also emits the fp16 copy
// of the output row for the next layer's gathers.
// x_out[n] = 0.5*x_in[n] + 0.5 * (sum_e x16_in[src[e]]*sim[e]) / max(deg,1)
// ---------------------------------------------------------------------------
template<bool WRITE16>
__global__ __launch_bounds__(384) void aggregate_kernel(
        const float* __restrict__ xin32, const uint2* __restrict__ xin16,
        const int* __restrict__ cnt, const int2* __restrict__ bucket,
        float* __restrict__ xout, uint2* __restrict__ xout16, int N) {
    int n = blockIdx.x;
    int t = threadIdx.x;
    int deg = cnt[n];               // uniform -> scalar load
    int m = min(deg, SLOTS);

    __shared__ int    s_src[SLOTS];
    __shared__ float  s_sim[SLOTS];
    __shared__ float4 s_red[4][D4];

    // issue the self-row load early (epilogue threads only)
    float4 xi = make_float4(0.f, 0.f, 0.f, 0.f);
    if (t < D4) xi = ((const float4*)xin32)[(size_t)n * D4 + t];

    if (t < m) {
        int2 p = bucket[(size_t)n * SLOTS + t];
        s_src[t] = p.x;
        s_sim[t] = __int_as_float(p.y);
    }
    __syncthreads();

    int g = t / D4, r = t - g * D4;

    float4 a0 = make_float4(0.f, 0.f, 0.f, 0.f);
    float4 a1 = make_float4(0.f, 0.f, 0.f, 0.f);
    float4 a2 = make_float4(0.f, 0.f, 0.f, 0.f);
    float4 a3 = make_float4(0.f, 0.f, 0.f, 0.f);
    int k = g;
    for (; k + 12 < m; k += 16) {
        uint2 u0 = xin16[(size_t)s_src[k]      * DH + r];
        uint2 u1 = xin16[(size_t)s_src[k + 4]  * DH + r];
        uint2 u2 = xin16[(size_t)s_src[k + 8]  * DH + r];
        uint2 u3 = xin16[(size_t)s_src[k + 12] * DH + r];
        float w0 = s_sim[k], w1 = s_sim[k + 4], w2 = s_sim[k + 8], w3 = s_sim[k + 12];
        float4 v0 = h4_to_f4(u0), v1 = h4_to_f4(u1), v2 = h4_to_f4(u2), v3 = h4_to_f4(u3);
        a0.x += v0.x*w0; a0.y += v0.y*w0; a0.z += v0.z*w0; a0.w += v0.w*w0;
        a1.x += v1.x*w1; a1.y += v1.y*w1; a1.z += v1.z*w1; a1.w += v1.w*w1;
        a2.x += v2.x*w2; a2.y += v2.y*w2; a2.z += v2.z*w2; a2.w += v2.w*w2;
        a3.x += v3.x*w3; a3.y += v3.y*w3; a3.z += v3.z*w3; a3.w += v3.w*w3;
    }
    for (; k < m; k += 4) {
        uint2 u0 = xin16[(size_t)s_src[k] * DH + r];
        float w0 = s_sim[k];
        float4 v0 = h4_to_f4(u0);
        a0.x += v0.x*w0; a0.y += v0.y*w0; a0.z += v0.z*w0; a0.w += v0.w*w0;
    }
    a0.x += a1.x + a2.x + a3.x;
    a0.y += a1.y + a2.y + a3.y;
    a0.z += a1.z + a2.z + a3.z;
    a0.w += a1.w + a2.w + a3.w;
    s_red[g][r] = a0;
    __syncthreads();

    if (t < D4) {
        float4 acc;
        acc.x = s_red[0][t].x + s_red[1][t].x + s_red[2][t].x + s_red[3][t].x;
        acc.y = s_red[0][t].y + s_red[1][t].y + s_red[2][t].y + s_red[3][t].y;
        acc.z = s_red[0][t].z + s_red[1][t].z + s_red[2][t].z + s_red[3][t].z;
        acc.w = s_red[0][t].w + s_red[1][t].w + s_red[2][t].w + s_red[3][t].w;
        float scale = 0.5f / fmaxf((float)deg, 1.0f);
        float4 o;
        o.x = 0.5f*xi.x + acc.x*scale;
        o.y = 0.5f*xi.y + acc.y*scale;
        o.z = 0.5f*xi.z + acc.z*scale;
        o.w = 0.5f*xi.w + acc.w*scale;
        ((float4*)xout)[(size_t)n * D4 + t] = o;
        if (WRITE16)
            xout16[(size_t)n * DH + t] = f4_to_h4(o);
    }
}

// ---------------------------------------------------------------------------
extern "C" void kernel_launch(void* const* d_in, const int* in_sizes, int n_in,
                              void* d_out, int out_size, void* d_ws, size_t ws_size,
                              hipStream_t stream) {
    const float* x   = (const float*)d_in[0];
    const int*   ei  = (const int*)d_in[1];
    const float* ea  = (const float*)d_in[2];
    const float* qe  = (const float*)d_in[3];

    const int N = in_sizes[0] / D;      // 10000
    const int E = in_sizes[1] / 2;      // 160000
    const int* src = ei;
    const int* dst = ei + E;

    char* w = (char*)d_ws;
    size_t off = 0;
    auto alloc = [&](size_t bytes) {
        char* p = w + off;
        off = (off + bytes + 255) & ~(size_t)255;
        return p;
    };
    int*   cnt    = (int*)  alloc((size_t)N * 4);              // 40 KB
    int2*  bucket = (int2*) alloc((size_t)N * SLOTS * 8);      // 7.68 MB
    uint2* x16    = (uint2*)alloc((size_t)N * D * 2);          // 7.68 MB
    float* xbuf   = (float*)alloc((size_t)N * D * 4);          // 15.36 MB
    uint2* xbuf16 = (uint2*)alloc((size_t)N * D * 2);          // 7.68 MB
    (void)ws_size; (void)n_in; (void)out_size;

    (void)hipMemsetAsync(cnt, 0, (size_t)N * 4, stream);
    tohalf_kernel<<<1024, 256, 0, stream>>>(x, x16, N * D / 4);
    edge_kernel<<<(E + 15) / 16, 256, 0, stream>>>(ea, qe, src, dst, cnt, bucket, E);

    // layer 1: x -> xbuf (+ fp16 copy for layer-2 gathers)
    aggregate_kernel<true><<<N, 384, 0, stream>>>(x, x16, cnt, bucket, xbuf, xbuf16, N);
    // layer 2: xbuf -> out
    aggregate_kernel<false><<<N, 384, 0, stream>>>(xbuf, xbuf16, cnt, bucket, (float*)d_out, nullptr, N);
}

// Round 5
// 370.563 us; speedup vs baseline: 1.1408x; 1.0499x over previous
//
#include <hip/hip_runtime.h>
#include <hip/hip_fp16.h>

#define D 384
#define D4 96      // float4s per fp32 row
#define DU4 48     // uint4 (8 halfs, 16B) chunks per fp16 row
#define SLOTS 96   // max degree bucket; dst ~ Poisson(16), P(deg>96) ~ 0

typedef float vfloat4 __attribute__((ext_vector_type(4)));

__device__ __forceinline__ uint2 f4_to_h4(float4 v) {
    __half2 h0 = __float22half2_rn(make_float2(v.x, v.y));
    __half2 h1 = __float22half2_rn(make_float2(v.z, v.w));
    uint2 u;
    u.x = *(unsigned int*)&h0;
    u.y = *(unsigned int*)&h1;
    return u;
}
__device__ __forceinline__ float4 h8_lo(uint4 u) {
    float2 a = __half22float2(*(__half2*)&u.x);
    float2 b = __half22float2(*(__half2*)&u.y);
    return make_float4(a.x, a.y, b.x, b.y);
}
__device__ __forceinline__ float4 h8_hi(uint4 u) {
    float2 a = __half22float2(*(__half2*)&u.z);
    float2 b = __half22float2(*(__half2*)&u.w);
    return make_float4(a.x, a.y, b.x, b.y);
}

// ---------------------------------------------------------------------------
// Kernel 1 (fused): q-norm + per-edge cosine sim + packed bucket scatter
// + side-job: convert x row blockIdx.x to fp16 (removes the tohalf launch).
// 4 edges per WAVE; two consecutive ea rows = 192 float4 = 3 float4/lane,
// all 64 lanes load 6x16B up front, 8 interleaved butterfly reductions.
// Bucket slot = (src << 16) | fp16(sim)  (4 B).
// ---------------------------------------------------------------------------
__global__ __launch_bounds__(256) void edge_kernel(
        const float* __restrict__ ea, const float* __restrict__ q,
        const int* __restrict__ src, const int* __restrict__ dst,
        const float* __restrict__ x, uint2* __restrict__ x16,
        int* __restrict__ cnt, unsigned int* __restrict__ bucket,
        int E, int N) {
    __shared__ float s_q[D];
    __shared__ float s_red[4];
    __shared__ float s_invq;
    int t = threadIdx.x;

    float ssq = 0.f;
    for (int i = t; i < D; i += 256) { float v = q[i]; s_q[i] = v; ssq += v * v; }

    // conversion side-job: block b converts fp32 row(s) b, b+grid, ... to fp16
    for (int row = blockIdx.x; row < N; row += gridDim.x)
        if (t < D4) {
            float4 v = ((const float4*)x)[(size_t)row * D4 + t];
            x16[(size_t)row * D4 + t] = f4_to_h4(v);
        }

    for (int s = 32; s > 0; s >>= 1) ssq += __shfl_down(ssq, s);
    if ((t & 63) == 0) s_red[t >> 6] = ssq;
    __syncthreads();
    if (t == 0)
        s_invq = 1.0f / fmaxf(sqrtf(s_red[0] + s_red[1] + s_red[2] + s_red[3]), 1e-12f);
    __syncthreads();

    int wave = t >> 6, lane = t & 63;
    int e0 = (blockIdx.x * 4 + wave) * 4;
    if (e0 >= E) return;

    const vfloat4* q4 = (const vfloat4*)s_q;
    bool lo = lane < 32;

    if (e0 + 4 <= E) {
        vfloat4 qc0 = q4[lane];
        vfloat4 qc1 = lo ? q4[lane + 64] : q4[lane - 32];
        vfloat4 qc2 = q4[lane + 32];

        const vfloat4* sp0 = (const vfloat4*)(ea + (size_t)e0 * D);
        const vfloat4* sp1 = (const vfloat4*)(ea + (size_t)(e0 + 2) * D);

        vfloat4 a0 = __builtin_nontemporal_load(&sp0[lane]);
        vfloat4 b0 = __builtin_nontemporal_load(&sp0[lane + 64]);
        vfloat4 c0 = __builtin_nontemporal_load(&sp0[lane + 128]);
        vfloat4 a1 = __builtin_nontemporal_load(&sp1[lane]);
        vfloat4 b1 = __builtin_nontemporal_load(&sp1[lane + 64]);
        vfloat4 c1 = __builtin_nontemporal_load(&sp1[lane + 128]);

        float dA0 = a0.x*qc0.x + a0.y*qc0.y + a0.z*qc0.z + a0.w*qc0.w;
        float sA0 = a0.x*a0.x + a0.y*a0.y + a0.z*a0.z + a0.w*a0.w;
        float db0 = b0.x*qc1.x + b0.y*qc1.y + b0.z*qc1.z + b0.w*qc1.w;
        float sb0 = b0.x*b0.x + b0.y*b0.y + b0.z*b0.z + b0.w*b0.w;
        float dB0 = c0.x*qc2.x + c0.y*qc2.y + c0.z*qc2.z + c0.w*qc2.w;
        float sB0 = c0.x*c0.x + c0.y*c0.y + c0.z*c0.z + c0.w*c0.w;
        if (lo) { dA0 += db0; sA0 += sb0; }
        else    { dB0 += db0; sB0 += sb0; }

        float dA1 = a1.x*qc0.x + a1.y*qc0.y + a1.z*qc0.z + a1.w*qc0.w;
        float sA1 = a1.x*a1.x + a1.y*a1.y + a1.z*a1.z + a1.w*a1.w;
        float db1 = b1.x*qc1.x + b1.y*qc1.y + b1.z*qc1.z + b1.w*qc1.w;
        float sb1 = b1.x*b1.x + b1.y*b1.y + b1.z*b1.z + b1.w*b1.w;
        float dB1 = c1.x*qc2.x + c1.y*qc2.y + c1.z*qc2.z + c1.w*qc2.w;
        float sB1 = c1.x*c1.x + c1.y*c1.y + c1.z*c1.z + c1.w*c1.w;
        if (lo) { dA1 += db1; sA1 += sb1; }
        else    { dB1 += db1; sB1 += sb1; }

        for (int s = 1; s < 64; s <<= 1) {
            dA0 += __shfl_xor(dA0, s); sA0 += __shfl_xor(sA0, s);
            dB0 += __shfl_xor(dB0, s); sB0 += __shfl_xor(sB0, s);
            dA1 += __shfl_xor(dA1, s); sA1 += __shfl_xor(sA1, s);
            dB1 += __shfl_xor(dB1, s); sB1 += __shfl_xor(sB1, s);
        }

        if (lane < 4) {
            int e = e0 + lane;
            float dt = (lane == 0) ? dA0 : (lane == 1) ? dB0 : (lane == 2) ? dA1 : dB1;
            float s2 = (lane == 0) ? sA0 : (lane == 1) ? sB0 : (lane == 2) ? sA1 : sB1;
            float sim = dt * s_invq / fmaxf(sqrtf(s2), 1e-12f);
            int n = dst[e];
            int sv = src[e];
            unsigned int word = ((unsigned int)sv << 16) |
                                (unsigned int)__half_as_ushort(__float2half_rn(sim));
            int p = atomicAdd(&cnt[n], 1);
            if (p < SLOTS)  // never taken for this input; safety only
                bucket[(size_t)n * SLOTS + p] = word;
        }
    } else {
        int ne = E - e0;
        for (int j = 0; j < ne; ++j) {
            const vfloat4* row = (const vfloat4*)(ea + (size_t)(e0 + j) * D);
            vfloat4 v = __builtin_nontemporal_load(&row[lane]);
            vfloat4 qq = q4[lane];
            float dot = v.x*qq.x + v.y*qq.y + v.z*qq.z + v.w*qq.w;
            float ss  = v.x*v.x + v.y*v.y + v.z*v.z + v.w*v.w;
            if (lo) {
                vfloat4 v2 = __builtin_nontemporal_load(&row[lane + 64]);
                vfloat4 q2 = q4[lane + 64];
                dot += v2.x*q2.x + v2.y*q2.y + v2.z*q2.z + v2.w*q2.w;
                ss  += v2.x*v2.x + v2.y*v2.y + v2.z*v2.z + v2.w*v2.w;
            }
            for (int s = 32; s > 0; s >>= 1) {
                dot += __shfl_down(dot, s);
                ss  += __shfl_down(ss, s);
            }
            if (lane == 0) {
                float sim = dot * s_invq / fmaxf(sqrtf(ss), 1e-12f);
                int n = dst[e0 + j];
                int sv = src[e0 + j];
                unsigned int word = ((unsigned int)sv << 16) |
                                    (unsigned int)__half_as_ushort(__float2half_rn(sim));
                int p = atomicAdd(&cnt[n], 1);
                if (p < SLOTS)
                    bucket[(size_t)n * SLOTS + p] = word;
            }
        }
    }
}

// ---------------------------------------------------------------------------
// Kernel 2: one layer. ONE NODE PER WAVE (256-thr block = 4 independent
// nodes -> 32 nodes in flight per CU, 4x the old 384-thr design). Lanes
// 0..47 each own one 16B fp16 chunk (8 halfs) of the row; each lane
// accumulates the FULL sum for its chunk across all m edges -> no
// inter-group reduce, single barrier. Gathers read fp16; self term fp32.
// x_out[n] = 0.5*x_in[n] + 0.5 * (sum_e x16_in[src[e]]*sim[e]) / max(deg,1)
// ---------------------------------------------------------------------------
template<bool WRITE16>
__global__ __launch_bounds__(256) void aggregate_kernel(
        const float* __restrict__ xin32, const uint4* __restrict__ xin16,
        const int* __restrict__ cnt, const unsigned int* __restrict__ bucket,
        float* __restrict__ xout, uint2* __restrict__ xout16, int N) {
    __shared__ unsigned int s_pk[4][SLOTS];
    int wv = threadIdx.x >> 6, lane = threadIdx.x & 63;
    int n = blockIdx.x * 4 + wv;

    int deg = 0, m = 0;
    if (n < N) {
        deg = cnt[n];                 // lane-uniform -> scalar
        m = min(deg, SLOTS);
    }
    const unsigned int* bk = bucket + (size_t)n * SLOTS;
    if (lane < m)       s_pk[wv][lane]      = bk[lane];        // slots 0..63
    if (lane + 64 < m)  s_pk[wv][lane + 64] = bk[lane + 64];   // slots 64..95 (lane<32)
    __syncthreads();

    if (n >= N || lane >= DU4) return;    // 48 active lanes per wave

    // self row (fp32), issued early: lane owns float4s 2*lane, 2*lane+1
    const float4* x32 = (const float4*)xin32;
    float4 xiA = x32[(size_t)n * D4 + 2 * lane];
    float4 xiB = x32[(size_t)n * D4 + 2 * lane + 1];

    float4 aA = make_float4(0.f, 0.f, 0.f, 0.f);
    float4 aB = make_float4(0.f, 0.f, 0.f, 0.f);

    int k = 0;
    for (; k + 3 < m; k += 4) {           // 4 independent 16B gathers in flight
        unsigned int p0 = s_pk[wv][k],     p1 = s_pk[wv][k + 1];
        unsigned int p2 = s_pk[wv][k + 2], p3 = s_pk[wv][k + 3];
        uint4 g0 = xin16[(size_t)(p0 >> 16) * DU4 + lane];
        uint4 g1 = xin16[(size_t)(p1 >> 16) * DU4 + lane];
        uint4 g2 = xin16[(size_t)(p2 >> 16) * DU4 + lane];
        uint4 g3 = xin16[(size_t)(p3 >> 16) * DU4 + lane];
        float w0 = __half2float(__ushort_as_half((unsigned short)p0));
        float w1 = __half2float(__ushort_as_half((unsigned short)p1));
        float w2 = __half2float(__ushort_as_half((unsigned short)p2));
        float w3 = __half2float(__ushort_as_half((unsigned short)p3));
        float4 l0 = h8_lo(g0), h0 = h8_hi(g0);
        float4 l1 = h8_lo(g1), h1 = h8_hi(g1);
        float4 l2 = h8_lo(g2), h2 = h8_hi(g2);
        float4 l3 = h8_lo(g3), h3 = h8_hi(g3);
        aA.x += l0.x*w0 + l1.x*w1 + l2.x*w2 + l3.x*w3;
        aA.y += l0.y*w0 + l1.y*w1 + l2.y*w2 + l3.y*w3;
        aA.z += l0.z*w0 + l1.z*w1 + l2.z*w2 + l3.z*w3;
        aA.w += l0.w*w0 + l1.w*w1 + l2.w*w2 + l3.w*w3;
        aB.x += h0.x*w0 + h1.x*w1 + h2.x*w2 + h3.x*w3;
        aB.y += h0.y*w0 + h1.y*w1 + h2.y*w2 + h3.y*w3;
        aB.z += h0.z*w0 + h1.z*w1 + h2.z*w2 + h3.z*w3;
        aB.w += h0.w*w0 + h1.w*w1 + h2.w*w2 + h3.w*w3;
    }
    for (; k < m; ++k) {
        unsigned int p0 = s_pk[wv][k];
        uint4 g0 = xin16[(size_t)(p0 >> 16) * DU4 + lane];
        float w0 = __half2float(__ushort_as_half((unsigned short)p0));
        float4 l0 = h8_lo(g0), h0 = h8_hi(g0);
        aA.x += l0.x*w0; aA.y += l0.y*w0; aA.z += l0.z*w0; aA.w += l0.w*w0;
        aB.x += h0.x*w0; aB.y += h0.y*w0; aB.z += h0.z*w0; aB.w += h0.w*w0;
    }

    float scale = 0.5f / fmaxf((float)deg, 1.0f);
    float4 oA, oB;
    oA.x = 0.5f*xiA.x + aA.x*scale;  oA.y = 0.5f*xiA.y + aA.y*scale;
    oA.z = 0.5f*xiA.z + aA.z*scale;  oA.w = 0.5f*xiA.w + aA.w*scale;
    oB.x = 0.5f*xiB.x + aB.x*scale;  oB.y = 0.5f*xiB.y + aB.y*scale;
    oB.z = 0.5f*xiB.z + aB.z*scale;  oB.w = 0.5f*xiB.w + aB.w*scale;
    ((float4*)xout)[(size_t)n * D4 + 2 * lane]     = oA;
    ((float4*)xout)[(size_t)n * D4 + 2 * lane + 1] = oB;
    if (WRITE16) {
        xout16[(size_t)n * D4 + 2 * lane]     = f4_to_h4(oA);
        xout16[(size_t)n * D4 + 2 * lane + 1] = f4_to_h4(oB);
    }
}

// ---------------------------------------------------------------------------
extern "C" void kernel_launch(void* const* d_in, const int* in_sizes, int n_in,
                              void* d_out, int out_size, void* d_ws, size_t ws_size,
                              hipStream_t stream) {
    const float* x   = (const float*)d_in[0];
    const int*   ei  = (const int*)d_in[1];
    const float* ea  = (const float*)d_in[2];
    const float* qe  = (const float*)d_in[3];

    const int N = in_sizes[0] / D;      // 10000
    const int E = in_sizes[1] / 2;      // 160000
    const int* src = ei;
    const int* dst = ei + E;

    char* w = (char*)d_ws;
    size_t off = 0;
    auto alloc = [&](size_t bytes) {
        char* p = w + off;
        off = (off + bytes + 255) & ~(size_t)255;
        return p;
    };
    int*          cnt    = (int*)          alloc((size_t)N * 4);           // 40 KB
    unsigned int* bucket = (unsigned int*) alloc((size_t)N * SLOTS * 4);   // 3.84 MB
    uint2*        x16    = (uint2*)        alloc((size_t)N * D * 2);       // 7.68 MB
    float*        xbuf   = (float*)        alloc((size_t)N * D * 4);       // 15.36 MB
    uint2*        xbuf16 = (uint2*)        alloc((size_t)N * D * 2);       // 7.68 MB
    (void)ws_size; (void)n_in; (void)out_size;

    (void)hipMemsetAsync(cnt, 0, (size_t)N * 4, stream);
    edge_kernel<<<(E + 15) / 16, 256, 0, stream>>>(ea, qe, src, dst, x, x16,
                                                   cnt, bucket, E, N);
    // layer 1: x -> xbuf (+ fp16 copy for layer-2 gathers)
    aggregate_kernel<true><<<(N + 3) / 4, 256, 0, stream>>>(
        x, (const uint4*)x16, cnt, bucket, xbuf, xbuf16, N);
    // layer 2: xbuf -> out
    aggregate_kernel<false><<<(N + 3) / 4, 256, 0, stream>>>(
        xbuf, (const uint4*)xbuf16, cnt, bucket, (float*)d_out, nullptr, N);
}